// Round 11
// baseline (277.084 us; speedup 1.0000x reference)
//
#include <hip/hip_runtime.h>

typedef unsigned short ushort;
typedef __bf16 bf16x8 __attribute__((ext_vector_type(8)));
typedef float f32x4 __attribute__((ext_vector_type(4)));
typedef unsigned short us8v __attribute__((ext_vector_type(8)));

__device__ __forceinline__ ushort f2bf(float f) {
  unsigned u = __builtin_bit_cast(unsigned, f);
  u += 0x7FFFu + ((u >> 16) & 1u);
  return (ushort)(u >> 16);
}

__device__ __forceinline__ bf16x8 ld_bf16x8(const ushort* p) {
  uint4 v = *(const uint4*)p;
  return __builtin_bit_cast(bf16x8, v);
}

// async global->LDS, 16B per lane (dest must be linear: base + lane*16)
__device__ __forceinline__ void gl16(const ushort* g, ushort* l) {
  __builtin_amdgcn_global_load_lds(
      (const __attribute__((address_space(1))) void*)g,
      (__attribute__((address_space(3))) void*)l, 16, 0, 0);
}

// ---------------- pack X fp32 -> bf16 ----------------
__global__ __launch_bounds__(256) void pack_x(const float* __restrict__ in,
                                              ushort* __restrict__ out) {
  long i = (long)blockIdx.x * 256 + threadIdx.x;
  const float4* s = (const float4*)in;
  float4 a = s[i * 2], b = s[i * 2 + 1];
  us8v o;
  o[0] = f2bf(a.x); o[1] = f2bf(a.y); o[2] = f2bf(a.z); o[3] = f2bf(a.w);
  o[4] = f2bf(b.x); o[5] = f2bf(b.y); o[6] = f2bf(b.z); o[7] = f2bf(b.w);
  *(us8v*)&out[i * 8] = o;
}

// ---------------- transpose+pack weights: dst[c][r] = src[r][c]*scale (bf16) ----
__global__ __launch_bounds__(256) void transpose_pack(
    const float* __restrict__ src, ushort* __restrict__ dst,
    int sC, int dLd, long sBatch, long dBatch, float scale) {
  src += (long)blockIdx.z * sBatch;
  dst += (long)blockIdx.z * dBatch;
  const int r0 = blockIdx.y * 64, c0 = blockIdx.x * 64;
  __shared__ ushort T[64 * 68];
  const int t = threadIdx.x;
#pragma unroll
  for (int i = 0; i < 4; ++i) {
    int ch = t + 256 * i;
    int r = ch >> 4, c4 = ch & 15;
    float4 v = *(const float4*)&src[(long)(r0 + r) * sC + c0 + c4 * 4];
    T[(c4 * 4 + 0) * 68 + r] = f2bf(v.x * scale);
    T[(c4 * 4 + 1) * 68 + r] = f2bf(v.y * scale);
    T[(c4 * 4 + 2) * 68 + r] = f2bf(v.z * scale);
    T[(c4 * 4 + 3) * 68 + r] = f2bf(v.w * scale);
  }
  __syncthreads();
#pragma unroll
  for (int i = 0; i < 4; ++i) {
    int ch = t + 256 * i;
    int c = ch >> 4, r4 = ch & 15;
    ushort4 o;
    o.x = T[c * 68 + r4 * 4 + 0];
    o.y = T[c * 68 + r4 * 4 + 1];
    o.z = T[c * 68 + r4 * 4 + 2];
    o.w = T[c * 68 + r4 * 4 + 3];
    *(ushort4*)&dst[(long)(c0 + c) * dLd + r0 + r4 * 4] = o;
  }
}

// ------ 256xBN bf16 MFMA GEMM, single-buffered (m97 structure), swizzled LDS --
// BM=256, BK=64, 8 waves (2 x 4). LDS = (256+BN)*64*2B single buffer -> 2
// blocks/CU co-residency hides the per-K-step vmcnt(0) drain (m114 overlap).
// XOR bank swizzle both sides: pre-swizzled global source col + swizzled
// ds_read col; LDS dest stays linear (global_load_lds requirement).
// EPI 0: scatter Q/K ([B,H,S,64]) + Vt ([B,D,S]); EPI 1: bf16 C; EPI 2: fp32 C
template <int EPI, bool CAUSAL, int BN>
__global__ __launch_bounds__(512, 2) void gemmS(
    const ushort* __restrict__ A, const ushort* __restrict__ Bt,
    int N, int K, long aB, long bB,
    ushort* __restrict__ O_q, ushort* __restrict__ O_k, ushort* __restrict__ O_v,
    ushort* __restrict__ O_b, long oB,
    float* __restrict__ O_f) {
  constexpr int NC = BN / 64;        // 16-col frags per wave (4 col-waves)
  __shared__ __align__(16) ushort As[256 * 64];
  __shared__ __align__(16) ushort Bs[BN * 64];
  const int tid = threadIdx.x;
  const int lane = tid & 63, w = tid >> 6;
  const int lr = lane & 15, lg = lane >> 4;

  // XCD-bijective swizzle (all grids used are a multiple of 8 blocks)
  const int nx = gridDim.x, ny = gridDim.y;
  long nwg = (long)nx * ny * gridDim.z;
  long hwid = blockIdx.x + (long)nx * (blockIdx.y + (long)ny * blockIdx.z);
  long cpx = nwg >> 3;
  long sid = (hwid & 7) * cpx + (hwid >> 3);
  int bx = (int)(sid % nx);
  int t2 = (int)(sid / nx);
  int by = t2 % ny, z = t2 / ny;

  const int row0 = by * 256, col0 = bx * BN;
  A += (long)z * aB;
  Bt += (long)z * bB;
  const int wrow = (w >> 2) * 128;            // 2 row-waves, 128 rows each
  const int wcol = (w & 3) * (BN / 4);        // 4 col-waves

  f32x4 acc[8][NC] = {};
  const int kmax = CAUSAL ? (K < row0 + 256 ? K : row0 + 256) : K;
  const int nk = kmax >> 6;

  for (int kt = 0; kt < nk; ++kt) {
    const int k0 = kt << 6;
    __syncthreads();                 // prior compute's LDS reads done
#pragma unroll
    for (int j = 0; j < 4; ++j) {    // A: 2048 16B-chunks / 512 thr
      int c = tid + 512 * j;
      int r = c >> 3, c8 = (c & 7) ^ (r & 7);
      gl16(&A[(long)(row0 + r) * K + k0 + c8 * 8], &As[c * 8]);
    }
#pragma unroll
    for (int j = 0; j < NC; ++j) {   // B: BN*8 chunks / 512 thr (exact)
      int c = tid + 512 * j;
      int r = c >> 3, c8 = (c & 7) ^ (r & 7);
      gl16(&Bt[(long)(col0 + r) * K + k0 + c8 * 8], &Bs[c * 8]);
    }
    __syncthreads();                 // vmcnt(0) drain: tile resident
#pragma unroll
    for (int kk = 0; kk < 2; ++kk) {
      bf16x8 bfr[NC];
#pragma unroll
      for (int n = 0; n < NC; ++n) {
        int row = wcol + n * 16 + lr;
        int c8 = (kk * 4 + lg) ^ (row & 7);
        bfr[n] = ld_bf16x8(&Bs[row * 64 + c8 * 8]);
      }
#pragma unroll
      for (int m = 0; m < 8; ++m) {
        int row = wrow + m * 16 + lr;
        int c8 = (kk * 4 + lg) ^ (row & 7);
        bf16x8 af = ld_bf16x8(&As[row * 64 + c8 * 8]);
#pragma unroll
        for (int n = 0; n < NC; ++n)
          acc[m][n] = __builtin_amdgcn_mfma_f32_16x16x32_bf16(af, bfr[n], acc[m][n], 0, 0, 0);
      }
    }
  }

#pragma unroll
  for (int m = 0; m < 8; ++m)
#pragma unroll
    for (int n = 0; n < NC; ++n)
#pragma unroll
      for (int r = 0; r < 4; ++r) {
        int gr = row0 + wrow + m * 16 + lg * 4 + r;
        int gc = col0 + wcol + n * 16 + lr;
        float v = acc[m][n][r];
        if (EPI == 0) {
          int b = gr >> 10, s = gr & 1023;
          if (gc < 1024) {
            int h = gc >> 6, kq = gc & 63;
            O_q[(((long)(b * 16 + h) << 10) + s) * 64 + kq] = f2bf(v);
          } else if (gc < 2048) {
            int n2 = gc - 1024;
            int h = n2 >> 6, kq = n2 & 63;
            O_k[(((long)(b * 16 + h) << 10) + s) * 64 + kq] = f2bf(v);
          } else {
            int e = gc - 2048;
            O_v[((long)(b << 10) + e) * 1024 + s] = f2bf(v);
          }
        } else if (EPI == 1) {
          (O_b + (long)z * oB)[(long)gr * N + gc] = f2bf(v);
        } else {
          O_f[(long)gr * N + gc] = v;
        }
      }
}

// ---------------- fused masked softmax, head-averaged attention (v5) ----------
// grid (64, 8) = 512 blocks, 512 threads = 8 waves, one 16-row q-tile/block.
// K staged per head into LDS via global_load_lds; XOR bank swizzle both sides.
// Next head's staging issued after barrier A, hidden under rescale. 2 barriers/head.
__global__ __launch_bounds__(512, 2) void attn16(
    const ushort* __restrict__ Qb, const ushort* __restrict__ Kb,
    const float* __restrict__ mask, float* __restrict__ attn_out,
    ushort* __restrict__ attnb) {
  __shared__ __align__(16) ushort Ks[8 * 128 * 64];  // 128 KB
  __shared__ float redS[8][16];
  const int tid = threadIdx.x;
  const int lane = tid & 63, w = tid >> 6;   // wave owns s-cols w*16+lr per 128-strip
  const int lr = lane & 15, lg = lane >> 4;
  const int hw = blockIdx.x + 64 * blockIdx.y;
  const int b = hw & 7;                      // linear id %8 = XCD: pin batch
  const int idx = hw >> 3;
  const int qt = (idx & 1) ? 63 - (idx >> 1) : (idx >> 1);
  const int q0 = qt * 16;
  const int NT = (qt >> 3) + 1;              // 128-strips needed (1..8)
  const int NTW = (qt >> 4) * 2 + 2;         // strips the 256-row AV tile reads
  const int nch = NT << 10;                  // 16B chunks to stage per head

  float mq[4], ms[8];
#pragma unroll
  for (int r = 0; r < 4; ++r) mq[r] = mask[b * 1024 + q0 + lg * 4 + r];
#pragma unroll
  for (int t = 0; t < 8; ++t) ms[t] = mask[b * 1024 + t * 128 + w * 16 + lr];

  // stage head 0 (source column pre-swizzled: LDS[st][r][c8] = G[st][r][c8^(r&7)])
  {
    const long hb = ((long)(b * 16)) << 10;
#pragma unroll 2
    for (int i = tid; i < nch; i += 512) {
      int st = i >> 10, r = (i >> 3) & 127, c8 = i & 7;
      gl16(&Kb[(hb + st * 128 + r) * 64 + ((c8 ^ (r & 7)) << 3)], &Ks[i * 8]);
    }
  }
  __syncthreads();  // pre-barrier drain completes the stage

  const int row = w * 16 + lr;
  const int cs0 = ((0 + lg) ^ (row & 7)) * 8;   // swizzled byte cols for kk=0/1
  const int cs1 = ((4 + lg) ^ (row & 7)) * 8;

  f32x4 acc[8] = {};
#pragma unroll 1
  for (int h = 0; h < 16; ++h) {
    const long hb = ((long)(b * 16 + h)) << 10;
    const bf16x8 qf0 = ld_bf16x8(&Qb[(hb + q0 + lr) * 64 + lg * 8]);
    const bf16x8 qf1 = ld_bf16x8(&Qb[(hb + q0 + lr) * 64 + 32 + lg * 8]);
    f32x4 sc[8];
    float ps[4] = {0.f, 0.f, 0.f, 0.f};
#pragma unroll
    for (int t = 0; t < 8; ++t) {
      const int sb = t * 128 + w * 16;
      if (sb <= q0) {                        // wave-uniform causal strip skip
        const ushort* kr = &Ks[t * 8192 + row * 64];
        bf16x8 k0 = ld_bf16x8(kr + cs0);
        bf16x8 k1 = ld_bf16x8(kr + cs1);
        f32x4 d = {};
        d = __builtin_amdgcn_mfma_f32_16x16x32_bf16(qf0, k0, d, 0, 0, 0);
        d = __builtin_amdgcn_mfma_f32_16x16x32_bf16(qf1, k1, d, 0, 0, 0);
#pragma unroll
        for (int r = 0; r < 4; ++r) {
          float e = __expf(d[r]) * (mq[r] * ms[t]);
          if (sb == q0) e = (lr <= lg * 4 + r) ? e : 0.f;  // diagonal strip
          sc[t][r] = e;
          ps[r] += e;
        }
      }
    }
    // row-sum: 16-lane shfl reduce, then cross-wave via LDS
#pragma unroll
    for (int r = 0; r < 4; ++r) {
      ps[r] += __shfl_xor(ps[r], 1);
      ps[r] += __shfl_xor(ps[r], 2);
      ps[r] += __shfl_xor(ps[r], 4);
      ps[r] += __shfl_xor(ps[r], 8);
    }
    if (lr == 0) {
#pragma unroll
      for (int r = 0; r < 4; ++r) redS[w][lg * 4 + r] = ps[r];
    }
    __syncthreads();  // (A): Ks reads done + redS visible

    if (h < 15) {     // issue next head's staging; hides under rescale below
      const long hb2 = ((long)(b * 16 + h + 1)) << 10;
#pragma unroll 2
      for (int i = tid; i < nch; i += 512) {
        int st = i >> 10, r = (i >> 3) & 127, c8 = i & 7;
        gl16(&Kb[(hb2 + st * 128 + r) * 64 + ((c8 ^ (r & 7)) << 3)], &Ks[i * 8]);
      }
    }

#pragma unroll
    for (int r = 0; r < 4; ++r) {
      float tot = 0.f;
#pragma unroll
      for (int ww = 0; ww < 8; ++ww) tot += redS[ww][lg * 4 + r];
      float rinv = __builtin_amdgcn_rcpf(tot);
#pragma unroll
      for (int t = 0; t < 8; ++t) {
        const int sb = t * 128 + w * 16;
        if (sb <= q0) acc[t][r] += sc[t][r] * rinv;
      }
    }
    if (h < 15) __syncthreads();  // (B): pre-barrier drain completes staging
  }  // heads

  // write fp32 attn_avg (d_out) + bf16 copy for strips the AV GEMM reads
#pragma unroll
  for (int t = 0; t < 8; ++t) {
    int s = t * 128 + w * 16 + lr;
#pragma unroll
    for (int r = 0; r < 4; ++r) {
      int q = q0 + lg * 4 + r;
      float v = acc[t][r] * 0.0625f;
      long o = ((long)(b * 1024 + q) << 10) + s;
      attn_out[o] = v;
      if (t < NTW) attnb[o] = f2bf(v);
    }
  }
}

// ---------------- launch ----------------
extern "C" void kernel_launch(void* const* d_in, const int* in_sizes, int n_in,
                              void* d_out, int out_size, void* d_ws, size_t ws_size,
                              hipStream_t stream) {
  const float* inputs = (const float*)d_in[0];
  const float* mask   = (const float*)d_in[1];
  const float* W_q    = (const float*)d_in[2];
  const float* W_k    = (const float*)d_in[3];
  const float* W_v    = (const float*)d_in[4];
  const float* W_o    = (const float*)d_in[5];
  float* out = (float*)d_out;

  ushort* Xb    = (ushort*)d_ws;            // [8192][1024]
  ushort* WqkvT = Xb + 8192L * 1024;        // [3072][1024]  (B^T layout)
  ushort* WoT   = WqkvT + 3072L * 1024;     // [1024][1024]
  ushort* Qb    = WoT + 1024L * 1024;       // [B,H,S,64]
  ushort* Kb    = Qb + 8L * 16 * 1024 * 64; // [B,H,S,64]
  ushort* Vt    = Kb + 8L * 16 * 1024 * 64; // [B,D,S]
  ushort* attnb = Vt + 8L * 1024 * 1024;    // [B,S,S]
  ushort* Houtb = attnb + 8L * 1024 * 1024; // [B,S,D]

  pack_x<<<4096, 256, 0, stream>>>(inputs, Xb);
  transpose_pack<<<dim3(1, 16, 16), 256, 0, stream>>>(W_q, WqkvT, 64, 1024,
                                                      65536L, 64L * 1024, 0.125f);
  transpose_pack<<<dim3(1, 16, 16), 256, 0, stream>>>(W_k, WqkvT + 1024L * 1024, 64, 1024,
                                                      65536L, 64L * 1024, 1.0f);
  transpose_pack<<<dim3(16, 16, 1), 256, 0, stream>>>(W_v, WqkvT + 2048L * 1024, 1024, 1024,
                                                      0L, 0L, 1.0f);
  transpose_pack<<<dim3(16, 16, 1), 256, 0, stream>>>(W_o, WoT, 1024, 1024,
                                                      0L, 0L, 1.0f);
  // QKV projection: [8192,1024] x [1024,3072], 256x192 tiles -> 512 blocks (2/CU)
  gemmS<0, false, 192><<<dim3(16, 32, 1), 512, 0, stream>>>(
      Xb, WqkvT, 3072, 1024, 0L, 0L, Qb, Kb, Vt, nullptr, 0L, nullptr);
  // masked softmax, head-avg
  attn16<<<dim3(64, 8), 512, 0, stream>>>(Qb, Kb, mask, out + 8388608L, attnb);
  // Hout = attn_avg @ V (causal K-limit), per batch, 256x128 tiles -> 256 blocks
  gemmS<1, true, 128><<<dim3(8, 4, 8), 512, 0, stream>>>(
      attnb, Vt, 1024, 1024, 1048576L, 1048576L,
      nullptr, nullptr, nullptr, Houtb, 1048576L, nullptr);
  // output = Hout @ W_o, 256x128 tiles -> 256 blocks
  gemmS<2, false, 128><<<dim3(8, 32, 1), 512, 0, stream>>>(
      Houtb, WoT, 1024, 1024, 0L, 0L,
      nullptr, nullptr, nullptr, nullptr, 0L, out);
}

// Round 12
// 250.490 us; speedup vs baseline: 1.1062x; 1.1062x over previous
//
#include <hip/hip_runtime.h>

typedef unsigned short ushort;
typedef __bf16 bf16x8 __attribute__((ext_vector_type(8)));
typedef float f32x4 __attribute__((ext_vector_type(4)));
typedef unsigned short us8v __attribute__((ext_vector_type(8)));

__device__ __forceinline__ ushort f2bf(float f) {
  unsigned u = __builtin_bit_cast(unsigned, f);
  u += 0x7FFFu + ((u >> 16) & 1u);
  return (ushort)(u >> 16);
}

__device__ __forceinline__ bf16x8 ld_bf16x8(const ushort* p) {
  uint4 v = *(const uint4*)p;
  return __builtin_bit_cast(bf16x8, v);
}

// async global->LDS, 16B per lane (dest must be linear: base + lane*16)
__device__ __forceinline__ void gl16(const ushort* g, ushort* l) {
  __builtin_amdgcn_global_load_lds(
      (const __attribute__((address_space(1))) void*)g,
      (__attribute__((address_space(3))) void*)l, 16, 0, 0);
}

// ---------------- pack X fp32 -> bf16 ----------------
__global__ __launch_bounds__(256) void pack_x(const float* __restrict__ in,
                                              ushort* __restrict__ out) {
  long i = (long)blockIdx.x * 256 + threadIdx.x;
  const float4* s = (const float4*)in;
  float4 a = s[i * 2], b = s[i * 2 + 1];
  us8v o;
  o[0] = f2bf(a.x); o[1] = f2bf(a.y); o[2] = f2bf(a.z); o[3] = f2bf(a.w);
  o[4] = f2bf(b.x); o[5] = f2bf(b.y); o[6] = f2bf(b.z); o[7] = f2bf(b.w);
  *(us8v*)&out[i * 8] = o;
}

// ---------------- transpose+pack weights: dst[c][r] = src[r][c]*scale (bf16) ----
__global__ __launch_bounds__(256) void transpose_pack(
    const float* __restrict__ src, ushort* __restrict__ dst,
    int sC, int dLd, long sBatch, long dBatch, float scale) {
  src += (long)blockIdx.z * sBatch;
  dst += (long)blockIdx.z * dBatch;
  const int r0 = blockIdx.y * 64, c0 = blockIdx.x * 64;
  __shared__ ushort T[64 * 68];
  const int t = threadIdx.x;
#pragma unroll
  for (int i = 0; i < 4; ++i) {
    int ch = t + 256 * i;
    int r = ch >> 4, c4 = ch & 15;
    float4 v = *(const float4*)&src[(long)(r0 + r) * sC + c0 + c4 * 4];
    T[(c4 * 4 + 0) * 68 + r] = f2bf(v.x * scale);
    T[(c4 * 4 + 1) * 68 + r] = f2bf(v.y * scale);
    T[(c4 * 4 + 2) * 68 + r] = f2bf(v.z * scale);
    T[(c4 * 4 + 3) * 68 + r] = f2bf(v.w * scale);
  }
  __syncthreads();
#pragma unroll
  for (int i = 0; i < 4; ++i) {
    int ch = t + 256 * i;
    int c = ch >> 4, r4 = ch & 15;
    ushort4 o;
    o.x = T[c * 68 + r4 * 4 + 0];
    o.y = T[c * 68 + r4 * 4 + 1];
    o.z = T[c * 68 + r4 * 4 + 2];
    o.w = T[c * 68 + r4 * 4 + 3];
    *(ushort4*)&dst[(long)(c0 + c) * dLd + r0 + r4 * 4] = o;
  }
}

// ------ 256xBN bf16 MFMA GEMM, single-buffered (m97 structure), swizzled LDS --
template <int EPI, bool CAUSAL, int BN>
__global__ __launch_bounds__(512, 2) void gemmS(
    const ushort* __restrict__ A, const ushort* __restrict__ Bt,
    int N, int K, long aB, long bB,
    ushort* __restrict__ O_q, ushort* __restrict__ O_k, ushort* __restrict__ O_v,
    ushort* __restrict__ O_b, long oB,
    float* __restrict__ O_f) {
  constexpr int NC = BN / 64;
  __shared__ __align__(16) ushort As[256 * 64];
  __shared__ __align__(16) ushort Bs[BN * 64];
  const int tid = threadIdx.x;
  const int lane = tid & 63, w = tid >> 6;
  const int lr = lane & 15, lg = lane >> 4;

  const int nx = gridDim.x, ny = gridDim.y;
  long nwg = (long)nx * ny * gridDim.z;
  long hwid = blockIdx.x + (long)nx * (blockIdx.y + (long)ny * blockIdx.z);
  long cpx = nwg >> 3;
  long sid = (hwid & 7) * cpx + (hwid >> 3);
  int bx = (int)(sid % nx);
  int t2 = (int)(sid / nx);
  int by = t2 % ny, z = t2 / ny;

  const int row0 = by * 256, col0 = bx * BN;
  A += (long)z * aB;
  Bt += (long)z * bB;
  const int wrow = (w >> 2) * 128;
  const int wcol = (w & 3) * (BN / 4);

  f32x4 acc[8][NC] = {};
  const int kmax = CAUSAL ? (K < row0 + 256 ? K : row0 + 256) : K;
  const int nk = kmax >> 6;

  for (int kt = 0; kt < nk; ++kt) {
    const int k0 = kt << 6;
    __syncthreads();
#pragma unroll
    for (int j = 0; j < 4; ++j) {
      int c = tid + 512 * j;
      int r = c >> 3, c8 = (c & 7) ^ (r & 7);
      gl16(&A[(long)(row0 + r) * K + k0 + c8 * 8], &As[c * 8]);
    }
#pragma unroll
    for (int j = 0; j < NC; ++j) {
      int c = tid + 512 * j;
      int r = c >> 3, c8 = (c & 7) ^ (r & 7);
      gl16(&Bt[(long)(col0 + r) * K + k0 + c8 * 8], &Bs[c * 8]);
    }
    __syncthreads();
#pragma unroll
    for (int kk = 0; kk < 2; ++kk) {
      bf16x8 bfr[NC];
#pragma unroll
      for (int n = 0; n < NC; ++n) {
        int row = wcol + n * 16 + lr;
        int c8 = (kk * 4 + lg) ^ (row & 7);
        bfr[n] = ld_bf16x8(&Bs[row * 64 + c8 * 8]);
      }
#pragma unroll
      for (int m = 0; m < 8; ++m) {
        int row = wrow + m * 16 + lr;
        int c8 = (kk * 4 + lg) ^ (row & 7);
        bf16x8 af = ld_bf16x8(&As[row * 64 + c8 * 8]);
#pragma unroll
        for (int n = 0; n < NC; ++n)
          acc[m][n] = __builtin_amdgcn_mfma_f32_16x16x32_bf16(af, bfr[n], acc[m][n], 0, 0, 0);
      }
    }
  }

#pragma unroll
  for (int m = 0; m < 8; ++m)
#pragma unroll
    for (int n = 0; n < NC; ++n)
#pragma unroll
      for (int r = 0; r < 4; ++r) {
        int gr = row0 + wrow + m * 16 + lg * 4 + r;
        int gc = col0 + wcol + n * 16 + lr;
        float v = acc[m][n][r];
        if (EPI == 0) {
          int b = gr >> 10, s = gr & 1023;
          if (gc < 1024) {
            int h = gc >> 6, kq = gc & 63;
            O_q[(((long)(b * 16 + h) << 10) + s) * 64 + kq] = f2bf(v);
          } else if (gc < 2048) {
            int n2 = gc - 1024;
            int h = n2 >> 6, kq = n2 & 63;
            O_k[(((long)(b * 16 + h) << 10) + s) * 64 + kq] = f2bf(v);
          } else {
            int e = gc - 2048;
            O_v[((long)(b << 10) + e) * 1024 + s] = f2bf(v);
          }
        } else if (EPI == 1) {
          (O_b + (long)z * oB)[(long)gr * N + gc] = f2bf(v);
        } else {
          O_f[(long)gr * N + gc] = v;
        }
      }
}

// ---------------- fused masked softmax, head-averaged attention (v6) ----------
// grid (32, 8) = 256 blocks (1/CU, 1 round), 512 threads = 8 waves. Block owns
// the PAIR (qt = x2, qt = 63-x2): uniform work, shared K staging. K staged per
// head into double-buffered LDS halves: Ks[0] = strips 0-3 (used by both
// tiles; heavy guard compile-time true), Ks[1] = strips 4-7 (heavy only).
// Stage(g1) issued before QK(g0); stage(next-head g0) issued before QK(g1):
// each drain barrier is covered by a full QK+exp phase. 2 barriers/head.
__global__ __launch_bounds__(512, 2) void attn16(
    const ushort* __restrict__ Qb, const ushort* __restrict__ Kb,
    const float* __restrict__ mask, float* __restrict__ attn_out,
    ushort* __restrict__ attnb) {
  __shared__ __align__(16) ushort Ks[2][4 * 128 * 64];  // 2 x 64 KB
  __shared__ float redS[2][8][16];
  const int tid = threadIdx.x;
  const int lane = tid & 63, w = tid >> 6;   // wave owns s-cols w*16+lr per 128-strip
  const int lr = lane & 15, lg = lane >> 4;
  const int hw = blockIdx.x + 32 * blockIdx.y;
  const int b = hw & 7;                      // linear id %8 = XCD: pin batch
  const int x2 = hw >> 3;                    // 0..31
  const int q0a = x2 * 16;                   // light tile (strips 0..3 only)
  const int q0b = (63 - x2) * 16;            // heavy tile (512..1008)
  const int NTb = ((63 - x2) >> 3) + 1;      // heavy strips needed: 5..8
  const int n1 = (NTb - 4) << 10;            // g1 chunk count (1024..4096)
  const int NTWa = (x2 >> 4) * 2 + 2;        // strips AV's 256-row tile reads
  const int NTWb = ((63 - x2) >> 4) * 2 + 2;

  float mqa[4], mqb[4], ms[8];
#pragma unroll
  for (int r = 0; r < 4; ++r) {
    mqa[r] = mask[b * 1024 + q0a + lg * 4 + r];
    mqb[r] = mask[b * 1024 + q0b + lg * 4 + r];
  }
#pragma unroll
  for (int t = 0; t < 8; ++t) ms[t] = mask[b * 1024 + t * 128 + w * 16 + lr];

  // stage group: strips [t0, t0+nch/1024) of head h into Ks[buf]
  // (source col pre-swizzled; LDS dest linear; read applies same XOR)
  auto stageG = [&](int buf, int t0, int nch, int h) {
    const long hb = ((long)(b * 16 + h)) << 10;
#pragma unroll 2
    for (int i = tid; i < nch; i += 512) {
      int j = i >> 10, r = (i >> 3) & 127, c8 = i & 7;
      gl16(&Kb[(hb + (t0 + j) * 128 + r) * 64 + ((c8 ^ (r & 7)) << 3)],
           &Ks[buf][i * 8]);
    }
  };

  const int row = w * 16 + lr;
  const int cs0 = ((0 + lg) ^ (row & 7)) * 8;   // swizzled byte cols kk=0/1
  const int cs1 = ((4 + lg) ^ (row & 7)) * 8;

  stageG(0, 0, 4096, 0);
  __syncthreads();   // prologue drain

  f32x4 acca[4] = {};
  f32x4 accb[8] = {};
#pragma unroll 1
  for (int h = 0; h < 16; ++h) {
    const long hb = ((long)(b * 16 + h)) << 10;
    const bf16x8 qa0 = ld_bf16x8(&Qb[(hb + q0a + lr) * 64 + lg * 8]);
    const bf16x8 qa1 = ld_bf16x8(&Qb[(hb + q0a + lr) * 64 + 32 + lg * 8]);
    const bf16x8 qb0 = ld_bf16x8(&Qb[(hb + q0b + lr) * 64 + lg * 8]);
    const bf16x8 qb1 = ld_bf16x8(&Qb[(hb + q0b + lr) * 64 + 32 + lg * 8]);

    stageG(1, 4, n1, h);   // issue g1 strips; covered by QK(g0) below

    f32x4 sca[4], scb[8];
    float psa[4] = {0.f, 0.f, 0.f, 0.f}, psb[4] = {0.f, 0.f, 0.f, 0.f};
    // ---- QK group 0: strips 0..3 from Ks[0] ----
#pragma unroll
    for (int t = 0; t < 4; ++t) {
      const int sb = t * 128 + w * 16;
      const ushort* kr = &Ks[0][(t * 128 + row) * 64];
      bf16x8 k0 = ld_bf16x8(kr + cs0);
      bf16x8 k1 = ld_bf16x8(kr + cs1);
      {  // heavy tile: sb <= 496 < 512 <= q0b always
        f32x4 d = {};
        d = __builtin_amdgcn_mfma_f32_16x16x32_bf16(qb0, k0, d, 0, 0, 0);
        d = __builtin_amdgcn_mfma_f32_16x16x32_bf16(qb1, k1, d, 0, 0, 0);
#pragma unroll
        for (int r = 0; r < 4; ++r) {
          float e = __expf(d[r]) * (mqb[r] * ms[t]);
          scb[t][r] = e;
          psb[r] += e;
        }
      }
      if (sb <= q0a) {  // light tile
        f32x4 d = {};
        d = __builtin_amdgcn_mfma_f32_16x16x32_bf16(qa0, k0, d, 0, 0, 0);
        d = __builtin_amdgcn_mfma_f32_16x16x32_bf16(qa1, k1, d, 0, 0, 0);
#pragma unroll
        for (int r = 0; r < 4; ++r) {
          float e = __expf(d[r]) * (mqa[r] * ms[t]);
          if (sb == q0a) e = (lr <= lg * 4 + r) ? e : 0.f;
          sca[t][r] = e;
          psa[r] += e;
        }
      }
    }
    __syncthreads();   // drain g1 stage; Ks[0] reads done

    if (h < 15) stageG(0, 0, 4096, h + 1);  // issue next head g0; covered by QK(g1)

    // ---- QK group 1: strips 4..7 from Ks[1] ----
#pragma unroll
    for (int t = 4; t < 8; ++t) {
      const int sb = t * 128 + w * 16;
      if (sb <= q0b) {
        const ushort* kr = &Ks[1][((t - 4) * 128 + row) * 64];
        bf16x8 k0 = ld_bf16x8(kr + cs0);
        bf16x8 k1 = ld_bf16x8(kr + cs1);
        f32x4 d = {};
        d = __builtin_amdgcn_mfma_f32_16x16x32_bf16(qb0, k0, d, 0, 0, 0);
        d = __builtin_amdgcn_mfma_f32_16x16x32_bf16(qb1, k1, d, 0, 0, 0);
#pragma unroll
        for (int r = 0; r < 4; ++r) {
          float e = __expf(d[r]) * (mqb[r] * ms[t]);
          if (sb == q0b) e = (lr <= lg * 4 + r) ? e : 0.f;
          scb[t][r] = e;
          psb[r] += e;
        }
      }
    }
    // row-sums: 16-lane shfl reduce, then cross-wave via LDS
#pragma unroll
    for (int r = 0; r < 4; ++r) {
      psa[r] += __shfl_xor(psa[r], 1);
      psa[r] += __shfl_xor(psa[r], 2);
      psa[r] += __shfl_xor(psa[r], 4);
      psa[r] += __shfl_xor(psa[r], 8);
      psb[r] += __shfl_xor(psb[r], 1);
      psb[r] += __shfl_xor(psb[r], 2);
      psb[r] += __shfl_xor(psb[r], 4);
      psb[r] += __shfl_xor(psb[r], 8);
    }
    if (lr == 0) {
#pragma unroll
      for (int r = 0; r < 4; ++r) {
        redS[0][w][lg * 4 + r] = psa[r];
        redS[1][w][lg * 4 + r] = psb[r];
      }
    }
    __syncthreads();  // drain next-g0 stage; Ks[1] reads done; redS visible

#pragma unroll
    for (int r = 0; r < 4; ++r) {
      float ta = 0.f, tb = 0.f;
#pragma unroll
      for (int ww = 0; ww < 8; ++ww) {
        ta += redS[0][ww][lg * 4 + r];
        tb += redS[1][ww][lg * 4 + r];
      }
      float ra = __builtin_amdgcn_rcpf(ta);
      float rb = __builtin_amdgcn_rcpf(tb);
#pragma unroll
      for (int t = 0; t < 4; ++t) {
        const int sb = t * 128 + w * 16;
        if (sb <= q0a) acca[t][r] += sca[t][r] * ra;
      }
#pragma unroll
      for (int t = 0; t < 8; ++t) {
        const int sb = t * 128 + w * 16;
        if (sb <= q0b) accb[t][r] += scb[t][r] * rb;
      }
    }
  }  // heads

  // write fp32 attn_avg (d_out) + bf16 copy for strips the AV GEMM reads
#pragma unroll
  for (int t = 0; t < 8; ++t) {
    int s = t * 128 + w * 16 + lr;
#pragma unroll
    for (int r = 0; r < 4; ++r) {
      {
        int q = q0a + lg * 4 + r;
        float v = (t < 4 ? acca[t][r] : 0.f) * 0.0625f;
        long o = ((long)(b * 1024 + q) << 10) + s;
        attn_out[o] = v;
        if (t < NTWa) attnb[o] = f2bf(v);
      }
      {
        int q = q0b + lg * 4 + r;
        float v = accb[t][r] * 0.0625f;
        long o = ((long)(b * 1024 + q) << 10) + s;
        attn_out[o] = v;
        if (t < NTWb) attnb[o] = f2bf(v);
      }
    }
  }
}

// ---------------- launch ----------------
extern "C" void kernel_launch(void* const* d_in, const int* in_sizes, int n_in,
                              void* d_out, int out_size, void* d_ws, size_t ws_size,
                              hipStream_t stream) {
  const float* inputs = (const float*)d_in[0];
  const float* mask   = (const float*)d_in[1];
  const float* W_q    = (const float*)d_in[2];
  const float* W_k    = (const float*)d_in[3];
  const float* W_v    = (const float*)d_in[4];
  const float* W_o    = (const float*)d_in[5];
  float* out = (float*)d_out;

  ushort* Xb    = (ushort*)d_ws;            // [8192][1024]
  ushort* WqkvT = Xb + 8192L * 1024;        // [3072][1024]  (B^T layout)
  ushort* WoT   = WqkvT + 3072L * 1024;     // [1024][1024]
  ushort* Qb    = WoT + 1024L * 1024;       // [B,H,S,64]
  ushort* Kb    = Qb + 8L * 16 * 1024 * 64; // [B,H,S,64]
  ushort* Vt    = Kb + 8L * 16 * 1024 * 64; // [B,D,S]
  ushort* attnb = Vt + 8L * 1024 * 1024;    // [B,S,S]
  ushort* Houtb = attnb + 8L * 1024 * 1024; // [B,S,D]

  pack_x<<<4096, 256, 0, stream>>>(inputs, Xb);
  transpose_pack<<<dim3(1, 16, 16), 256, 0, stream>>>(W_q, WqkvT, 64, 1024,
                                                      65536L, 64L * 1024, 0.125f);
  transpose_pack<<<dim3(1, 16, 16), 256, 0, stream>>>(W_k, WqkvT + 1024L * 1024, 64, 1024,
                                                      65536L, 64L * 1024, 1.0f);
  transpose_pack<<<dim3(16, 16, 1), 256, 0, stream>>>(W_v, WqkvT + 2048L * 1024, 1024, 1024,
                                                      0L, 0L, 1.0f);
  transpose_pack<<<dim3(16, 16, 1), 256, 0, stream>>>(W_o, WoT, 1024, 1024,
                                                      0L, 0L, 1.0f);
  // QKV projection: [8192,1024] x [1024,3072], 256x192 tiles -> 512 blocks (2/CU)
  gemmS<0, false, 192><<<dim3(16, 32, 1), 512, 0, stream>>>(
      Xb, WqkvT, 3072, 1024, 0L, 0L, Qb, Kb, Vt, nullptr, 0L, nullptr);
  // masked softmax, head-avg: 256 blocks, paired q-tiles
  attn16<<<dim3(32, 8), 512, 0, stream>>>(Qb, Kb, mask, out + 8388608L, attnb);
  // Hout = attn_avg @ V (causal K-limit), per batch, 256x128 tiles -> 256 blocks
  gemmS<1, true, 128><<<dim3(8, 4, 8), 512, 0, stream>>>(
      attnb, Vt, 1024, 1024, 1048576L, 1048576L,
      nullptr, nullptr, nullptr, Houtb, 1048576L, nullptr);
  // output = Hout @ W_o, 256x128 tiles -> 256 blocks
  gemmS<2, false, 128><<<dim3(8, 32, 1), 512, 0, stream>>>(
      Houtb, WoT, 1024, 1024, 0L, 0L,
      nullptr, nullptr, nullptr, nullptr, 0L, out);
}

// Round 13
// 248.040 us; speedup vs baseline: 1.1171x; 1.0099x over previous
//
#include <hip/hip_runtime.h>

typedef unsigned short ushort;
typedef __bf16 bf16x8 __attribute__((ext_vector_type(8)));
typedef float f32x4 __attribute__((ext_vector_type(4)));
typedef unsigned short us8v __attribute__((ext_vector_type(8)));

__device__ __forceinline__ ushort f2bf(float f) {
  unsigned u = __builtin_bit_cast(unsigned, f);
  u += 0x7FFFu + ((u >> 16) & 1u);
  return (ushort)(u >> 16);
}

__device__ __forceinline__ bf16x8 ld_bf16x8(const ushort* p) {
  uint4 v = *(const uint4*)p;
  return __builtin_bit_cast(bf16x8, v);
}

// async global->LDS, 16B per lane (dest must be linear: base + lane*16)
__device__ __forceinline__ void gl16(const ushort* g, ushort* l) {
  __builtin_amdgcn_global_load_lds(
      (const __attribute__((address_space(1))) void*)g,
      (__attribute__((address_space(3))) void*)l, 16, 0, 0);
}

// ---------------- pack X fp32 -> bf16 ----------------
__global__ __launch_bounds__(256) void pack_x(const float* __restrict__ in,
                                              ushort* __restrict__ out) {
  long i = (long)blockIdx.x * 256 + threadIdx.x;
  const float4* s = (const float4*)in;
  float4 a = s[i * 2], b = s[i * 2 + 1];
  us8v o;
  o[0] = f2bf(a.x); o[1] = f2bf(a.y); o[2] = f2bf(a.z); o[3] = f2bf(a.w);
  o[4] = f2bf(b.x); o[5] = f2bf(b.y); o[6] = f2bf(b.z); o[7] = f2bf(b.w);
  *(us8v*)&out[i * 8] = o;
}

// ---------------- transpose+pack weights: dst[c][r] = src[r][c]*scale (bf16) ----
__global__ __launch_bounds__(256) void transpose_pack(
    const float* __restrict__ src, ushort* __restrict__ dst,
    int sC, int dLd, long sBatch, long dBatch, float scale) {
  src += (long)blockIdx.z * sBatch;
  dst += (long)blockIdx.z * dBatch;
  const int r0 = blockIdx.y * 64, c0 = blockIdx.x * 64;
  __shared__ ushort T[64 * 68];
  const int t = threadIdx.x;
#pragma unroll
  for (int i = 0; i < 4; ++i) {
    int ch = t + 256 * i;
    int r = ch >> 4, c4 = ch & 15;
    float4 v = *(const float4*)&src[(long)(r0 + r) * sC + c0 + c4 * 4];
    T[(c4 * 4 + 0) * 68 + r] = f2bf(v.x * scale);
    T[(c4 * 4 + 1) * 68 + r] = f2bf(v.y * scale);
    T[(c4 * 4 + 2) * 68 + r] = f2bf(v.z * scale);
    T[(c4 * 4 + 3) * 68 + r] = f2bf(v.w * scale);
  }
  __syncthreads();
#pragma unroll
  for (int i = 0; i < 4; ++i) {
    int ch = t + 256 * i;
    int c = ch >> 4, r4 = ch & 15;
    ushort4 o;
    o.x = T[c * 68 + r4 * 4 + 0];
    o.y = T[c * 68 + r4 * 4 + 1];
    o.z = T[c * 68 + r4 * 4 + 2];
    o.w = T[c * 68 + r4 * 4 + 3];
    *(ushort4*)&dst[(long)(c0 + c) * dLd + r0 + r4 * 4] = o;
  }
}

// ------ 128x128 bf16 MFMA GEMM, m97 shape: 4 waves, 3 blocks/CU, swizzled ----
// 256 thr, 64 AGPR acc -> ~164 total regs -> 3 waves/SIMD -> 3 blocks/CU:
// sibling blocks anti-phase the per-K-step vmcnt(0) drain (m114 overlap).
// XOR bank swizzle both sides (pre-swizzled global src col + swizzled ds_read).
// SWZ=0: bx-fastest XCD chunk (AV: pins batch z to XCD).
// SWZ=1: by-fastest XCD chunk (weight-stationary: B column-slice L2-resident).
// EPI 0: scatter Q/K ([B,H,S,64]) + Vt ([B,D,S]); EPI 1: bf16 C; EPI 2: fp32 C
template <int EPI, bool CAUSAL, int SWZ>
__global__ __launch_bounds__(256, 3) void gemm4(
    const ushort* __restrict__ A, const ushort* __restrict__ Bt,
    int N, int K, long aB, long bB,
    ushort* __restrict__ O_q, ushort* __restrict__ O_k, ushort* __restrict__ O_v,
    ushort* __restrict__ O_b, long oB,
    float* __restrict__ O_f) {
  __shared__ __align__(16) ushort As[128 * 64];
  __shared__ __align__(16) ushort Bs[128 * 64];
  const int tid = threadIdx.x;
  const int lane = tid & 63, w = tid >> 6;
  const int lr = lane & 15, lg = lane >> 4;

  // XCD-bijective swizzle (all grids used are a multiple of 8 blocks)
  const int nx = gridDim.x, ny = gridDim.y;
  long nwg = (long)nx * ny * gridDim.z;
  long hwid = blockIdx.x + (long)nx * (blockIdx.y + (long)ny * blockIdx.z);
  long cpx = nwg >> 3;
  long sid = (hwid & 7) * cpx + (hwid >> 3);
  int bx, by, z;
  if (SWZ == 1) {            // by-fastest: XCD owns a B column slice
    by = (int)(sid % ny);
    int t2 = (int)(sid / ny);
    bx = t2 % nx;
    z = t2 / nx;
  } else {                   // bx-fastest: XCD owns batches (z)
    bx = (int)(sid % nx);
    int t2 = (int)(sid / nx);
    by = t2 % ny;
    z = t2 / ny;
  }

  const int row0 = by * 128, col0 = bx * 128;
  A += (long)z * aB;
  Bt += (long)z * bB;
  const int wr = (w >> 1) * 64, wc = (w & 1) * 64;

  f32x4 acc[4][4] = {};
  const int kmax = CAUSAL ? (K < row0 + 128 ? K : row0 + 128) : K;
  const int nk = kmax >> 6;

  for (int kt = 0; kt < nk; ++kt) {
    const int k0 = kt << 6;
    __syncthreads();                 // prior compute's LDS reads done
#pragma unroll
    for (int j = 0; j < 4; ++j) {    // A,B: 1024 16B-chunks each / 256 thr
      int c = tid + 256 * j;
      int r = c >> 3, c8 = (c & 7) ^ (r & 7);
      gl16(&A[(long)(row0 + r) * K + k0 + c8 * 8], &As[c * 8]);
      gl16(&Bt[(long)(col0 + r) * K + k0 + c8 * 8], &Bs[c * 8]);
    }
    __syncthreads();                 // vmcnt(0) drain: tile resident
#pragma unroll
    for (int kk = 0; kk < 2; ++kk) {
      bf16x8 af[4], bfr[4];
#pragma unroll
      for (int m = 0; m < 4; ++m) {
        int row = wr + m * 16 + lr;
        int c8 = (kk * 4 + lg) ^ (row & 7);
        af[m] = ld_bf16x8(&As[row * 64 + c8 * 8]);
      }
#pragma unroll
      for (int n = 0; n < 4; ++n) {
        int row = wc + n * 16 + lr;
        int c8 = (kk * 4 + lg) ^ (row & 7);
        bfr[n] = ld_bf16x8(&Bs[row * 64 + c8 * 8]);
      }
#pragma unroll
      for (int m = 0; m < 4; ++m)
#pragma unroll
        for (int n = 0; n < 4; ++n)
          acc[m][n] = __builtin_amdgcn_mfma_f32_16x16x32_bf16(af[m], bfr[n], acc[m][n], 0, 0, 0);
    }
  }

#pragma unroll
  for (int m = 0; m < 4; ++m)
#pragma unroll
    for (int n = 0; n < 4; ++n)
#pragma unroll
      for (int r = 0; r < 4; ++r) {
        int gr = row0 + wr + m * 16 + lg * 4 + r;
        int gc = col0 + wc + n * 16 + lr;
        float v = acc[m][n][r];
        if (EPI == 0) {
          int b = gr >> 10, s = gr & 1023;
          if (gc < 1024) {
            int h = gc >> 6, kq = gc & 63;
            O_q[(((long)(b * 16 + h) << 10) + s) * 64 + kq] = f2bf(v);
          } else if (gc < 2048) {
            int n2 = gc - 1024;
            int h = n2 >> 6, kq = n2 & 63;
            O_k[(((long)(b * 16 + h) << 10) + s) * 64 + kq] = f2bf(v);
          } else {
            int e = gc - 2048;
            O_v[((long)(b << 10) + e) * 1024 + s] = f2bf(v);
          }
        } else if (EPI == 1) {
          (O_b + (long)z * oB)[(long)gr * N + gc] = f2bf(v);
        } else {
          O_f[(long)gr * N + gc] = v;
        }
      }
}

// ---------------- fused masked softmax, head-averaged attention (v6) ----------
// grid (32, 8) = 256 blocks (1/CU, 1 round), 512 threads = 8 waves. Block owns
// the PAIR (qt = x2, qt = 63-x2): uniform work, shared K staging. K staged per
// head into double-buffered LDS halves; stage drains covered by QK phases.
__global__ __launch_bounds__(512, 2) void attn16(
    const ushort* __restrict__ Qb, const ushort* __restrict__ Kb,
    const float* __restrict__ mask, float* __restrict__ attn_out,
    ushort* __restrict__ attnb) {
  __shared__ __align__(16) ushort Ks[2][4 * 128 * 64];  // 2 x 64 KB
  __shared__ float redS[2][8][16];
  const int tid = threadIdx.x;
  const int lane = tid & 63, w = tid >> 6;   // wave owns s-cols w*16+lr per 128-strip
  const int lr = lane & 15, lg = lane >> 4;
  const int hw = blockIdx.x + 32 * blockIdx.y;
  const int b = hw & 7;                      // linear id %8 = XCD: pin batch
  const int x2 = hw >> 3;                    // 0..31
  const int q0a = x2 * 16;                   // light tile (strips 0..3 only)
  const int q0b = (63 - x2) * 16;            // heavy tile (512..1008)
  const int NTb = ((63 - x2) >> 3) + 1;      // heavy strips needed: 5..8
  const int n1 = (NTb - 4) << 10;            // g1 chunk count (1024..4096)
  const int NTWa = (x2 >> 3) + 1;            // strips AV's 128-row tile reads
  const int NTWb = ((63 - x2) >> 3) + 1;

  float mqa[4], mqb[4], ms[8];
#pragma unroll
  for (int r = 0; r < 4; ++r) {
    mqa[r] = mask[b * 1024 + q0a + lg * 4 + r];
    mqb[r] = mask[b * 1024 + q0b + lg * 4 + r];
  }
#pragma unroll
  for (int t = 0; t < 8; ++t) ms[t] = mask[b * 1024 + t * 128 + w * 16 + lr];

  auto stageG = [&](int buf, int t0, int nch, int h) {
    const long hb = ((long)(b * 16 + h)) << 10;
#pragma unroll 2
    for (int i = tid; i < nch; i += 512) {
      int j = i >> 10, r = (i >> 3) & 127, c8 = i & 7;
      gl16(&Kb[(hb + (t0 + j) * 128 + r) * 64 + ((c8 ^ (r & 7)) << 3)],
           &Ks[buf][i * 8]);
    }
  };

  const int row = w * 16 + lr;
  const int cs0 = ((0 + lg) ^ (row & 7)) * 8;   // swizzled byte cols kk=0/1
  const int cs1 = ((4 + lg) ^ (row & 7)) * 8;

  stageG(0, 0, 4096, 0);
  __syncthreads();   // prologue drain

  f32x4 acca[4] = {};
  f32x4 accb[8] = {};
#pragma unroll 1
  for (int h = 0; h < 16; ++h) {
    const long hb = ((long)(b * 16 + h)) << 10;
    const bf16x8 qa0 = ld_bf16x8(&Qb[(hb + q0a + lr) * 64 + lg * 8]);
    const bf16x8 qa1 = ld_bf16x8(&Qb[(hb + q0a + lr) * 64 + 32 + lg * 8]);
    const bf16x8 qb0 = ld_bf16x8(&Qb[(hb + q0b + lr) * 64 + lg * 8]);
    const bf16x8 qb1 = ld_bf16x8(&Qb[(hb + q0b + lr) * 64 + 32 + lg * 8]);

    stageG(1, 4, n1, h);   // issue g1 strips; covered by QK(g0) below

    f32x4 sca[4], scb[8];
    float psa[4] = {0.f, 0.f, 0.f, 0.f}, psb[4] = {0.f, 0.f, 0.f, 0.f};
    // ---- QK group 0: strips 0..3 from Ks[0] ----
#pragma unroll
    for (int t = 0; t < 4; ++t) {
      const int sb = t * 128 + w * 16;
      const ushort* kr = &Ks[0][(t * 128 + row) * 64];
      bf16x8 k0 = ld_bf16x8(kr + cs0);
      bf16x8 k1 = ld_bf16x8(kr + cs1);
      {  // heavy tile: sb <= 496 < 512 <= q0b always
        f32x4 d = {};
        d = __builtin_amdgcn_mfma_f32_16x16x32_bf16(qb0, k0, d, 0, 0, 0);
        d = __builtin_amdgcn_mfma_f32_16x16x32_bf16(qb1, k1, d, 0, 0, 0);
#pragma unroll
        for (int r = 0; r < 4; ++r) {
          float e = __expf(d[r]) * (mqb[r] * ms[t]);
          scb[t][r] = e;
          psb[r] += e;
        }
      }
      if (sb <= q0a) {  // light tile
        f32x4 d = {};
        d = __builtin_amdgcn_mfma_f32_16x16x32_bf16(qa0, k0, d, 0, 0, 0);
        d = __builtin_amdgcn_mfma_f32_16x16x32_bf16(qa1, k1, d, 0, 0, 0);
#pragma unroll
        for (int r = 0; r < 4; ++r) {
          float e = __expf(d[r]) * (mqa[r] * ms[t]);
          if (sb == q0a) e = (lr <= lg * 4 + r) ? e : 0.f;
          sca[t][r] = e;
          psa[r] += e;
        }
      }
    }
    __syncthreads();   // drain g1 stage; Ks[0] reads done

    if (h < 15) stageG(0, 0, 4096, h + 1);  // issue next head g0; covered by QK(g1)

    // ---- QK group 1: strips 4..7 from Ks[1] ----
#pragma unroll
    for (int t = 4; t < 8; ++t) {
      const int sb = t * 128 + w * 16;
      if (sb <= q0b) {
        const ushort* kr = &Ks[1][((t - 4) * 128 + row) * 64];
        bf16x8 k0 = ld_bf16x8(kr + cs0);
        bf16x8 k1 = ld_bf16x8(kr + cs1);
        f32x4 d = {};
        d = __builtin_amdgcn_mfma_f32_16x16x32_bf16(qb0, k0, d, 0, 0, 0);
        d = __builtin_amdgcn_mfma_f32_16x16x32_bf16(qb1, k1, d, 0, 0, 0);
#pragma unroll
        for (int r = 0; r < 4; ++r) {
          float e = __expf(d[r]) * (mqb[r] * ms[t]);
          if (sb == q0b) e = (lr <= lg * 4 + r) ? e : 0.f;
          scb[t][r] = e;
          psb[r] += e;
        }
      }
    }
    // row-sums: 16-lane shfl reduce, then cross-wave via LDS
#pragma unroll
    for (int r = 0; r < 4; ++r) {
      psa[r] += __shfl_xor(psa[r], 1);
      psa[r] += __shfl_xor(psa[r], 2);
      psa[r] += __shfl_xor(psa[r], 4);
      psa[r] += __shfl_xor(psa[r], 8);
      psb[r] += __shfl_xor(psb[r], 1);
      psb[r] += __shfl_xor(psb[r], 2);
      psb[r] += __shfl_xor(psb[r], 4);
      psb[r] += __shfl_xor(psb[r], 8);
    }
    if (lr == 0) {
#pragma unroll
      for (int r = 0; r < 4; ++r) {
        redS[0][w][lg * 4 + r] = psa[r];
        redS[1][w][lg * 4 + r] = psb[r];
      }
    }
    __syncthreads();  // drain next-g0 stage; Ks[1] reads done; redS visible

#pragma unroll
    for (int r = 0; r < 4; ++r) {
      float ta = 0.f, tb = 0.f;
#pragma unroll
      for (int ww = 0; ww < 8; ++ww) {
        ta += redS[0][ww][lg * 4 + r];
        tb += redS[1][ww][lg * 4 + r];
      }
      float ra = __builtin_amdgcn_rcpf(ta);
      float rb = __builtin_amdgcn_rcpf(tb);
#pragma unroll
      for (int t = 0; t < 4; ++t) {
        const int sb = t * 128 + w * 16;
        if (sb <= q0a) acca[t][r] += sca[t][r] * ra;
      }
#pragma unroll
      for (int t = 0; t < 8; ++t) {
        const int sb = t * 128 + w * 16;
        if (sb <= q0b) accb[t][r] += scb[t][r] * rb;
      }
    }
  }  // heads

  // write fp32 attn_avg (d_out) + bf16 copy for strips the AV GEMM reads
#pragma unroll
  for (int t = 0; t < 8; ++t) {
    int s = t * 128 + w * 16 + lr;
#pragma unroll
    for (int r = 0; r < 4; ++r) {
      {
        int q = q0a + lg * 4 + r;
        float v = (t < 4 ? acca[t][r] : 0.f) * 0.0625f;
        long o = ((long)(b * 1024 + q) << 10) + s;
        attn_out[o] = v;
        if (t < NTWa) attnb[o] = f2bf(v);
      }
      {
        int q = q0b + lg * 4 + r;
        float v = accb[t][r] * 0.0625f;
        long o = ((long)(b * 1024 + q) << 10) + s;
        attn_out[o] = v;
        if (t < NTWb) attnb[o] = f2bf(v);
      }
    }
  }
}

// ---------------- launch ----------------
extern "C" void kernel_launch(void* const* d_in, const int* in_sizes, int n_in,
                              void* d_out, int out_size, void* d_ws, size_t ws_size,
                              hipStream_t stream) {
  const float* inputs = (const float*)d_in[0];
  const float* mask   = (const float*)d_in[1];
  const float* W_q    = (const float*)d_in[2];
  const float* W_k    = (const float*)d_in[3];
  const float* W_v    = (const float*)d_in[4];
  const float* W_o    = (const float*)d_in[5];
  float* out = (float*)d_out;

  ushort* Xb    = (ushort*)d_ws;            // [8192][1024]
  ushort* WqkvT = Xb + 8192L * 1024;        // [3072][1024]  (B^T layout)
  ushort* WoT   = WqkvT + 3072L * 1024;     // [1024][1024]
  ushort* Qb    = WoT + 1024L * 1024;       // [B,H,S,64]
  ushort* Kb    = Qb + 8L * 16 * 1024 * 64; // [B,H,S,64]
  ushort* Vt    = Kb + 8L * 16 * 1024 * 64; // [B,D,S]
  ushort* attnb = Vt + 8L * 1024 * 1024;    // [B,S,S]
  ushort* Houtb = attnb + 8L * 1024 * 1024; // [B,S,D]

  pack_x<<<4096, 256, 0, stream>>>(inputs, Xb);
  transpose_pack<<<dim3(1, 16, 16), 256, 0, stream>>>(W_q, WqkvT, 64, 1024,
                                                      65536L, 64L * 1024, 0.125f);
  transpose_pack<<<dim3(1, 16, 16), 256, 0, stream>>>(W_k, WqkvT + 1024L * 1024, 64, 1024,
                                                      65536L, 64L * 1024, 1.0f);
  transpose_pack<<<dim3(16, 16, 1), 256, 0, stream>>>(W_v, WqkvT + 2048L * 1024, 1024, 1024,
                                                      0L, 0L, 1.0f);
  transpose_pack<<<dim3(16, 16, 1), 256, 0, stream>>>(W_o, WoT, 1024, 1024,
                                                      0L, 0L, 1.0f);
  // QKV projection: [8192,1024] x [1024,3072], 128^2 tiles, 3 blocks/CU,
  // B-column L2 ownership (SWZ=1). 1536 blocks = 2 full rounds at 3/CU.
  gemm4<0, false, 1><<<dim3(24, 64, 1), 256, 0, stream>>>(
      Xb, WqkvT, 3072, 1024, 0L, 0L, Qb, Kb, Vt, nullptr, 0L, nullptr);
  // masked softmax, head-avg: 256 blocks, paired q-tiles
  attn16<<<dim3(32, 8), 512, 0, stream>>>(Qb, Kb, mask, out + 8388608L, attnb);
  // Hout = attn_avg @ V (causal K-limit), per batch (SWZ=0: z pinned to XCD)
  gemm4<1, true, 0><<<dim3(8, 8, 8), 256, 0, stream>>>(
      attnb, Vt, 1024, 1024, 1048576L, 1048576L,
      nullptr, nullptr, nullptr, Houtb, 1048576L, nullptr);
  // output = Hout @ W_o, B-column L2 ownership
  gemm4<2, false, 1><<<dim3(8, 64, 1), 256, 0, stream>>>(
      Houtb, WoT, 1024, 1024, 0L, 0L,
      nullptr, nullptr, nullptr, nullptr, 0L, out);
}

// Round 14
// 234.420 us; speedup vs baseline: 1.1820x; 1.0581x over previous
//
#include <hip/hip_runtime.h>

typedef unsigned short ushort;
typedef __bf16 bf16x8 __attribute__((ext_vector_type(8)));
typedef float f32x4 __attribute__((ext_vector_type(4)));
typedef unsigned short us8v __attribute__((ext_vector_type(8)));

__device__ __forceinline__ ushort f2bf(float f) {
  unsigned u = __builtin_bit_cast(unsigned, f);
  u += 0x7FFFu + ((u >> 16) & 1u);
  return (ushort)(u >> 16);
}

__device__ __forceinline__ bf16x8 ld_bf16x8(const ushort* p) {
  uint4 v = *(const uint4*)p;
  return __builtin_bit_cast(bf16x8, v);
}

// async global->LDS, 16B per lane (dest must be linear: base + lane*16)
__device__ __forceinline__ void gl16(const ushort* g, ushort* l) {
  __builtin_amdgcn_global_load_lds(
      (const __attribute__((address_space(1))) void*)g,
      (__attribute__((address_space(3))) void*)l, 16, 0, 0);
}

// ---------------- pack X fp32 -> bf16 ----------------
__global__ __launch_bounds__(256) void pack_x(const float* __restrict__ in,
                                              ushort* __restrict__ out) {
  long i = (long)blockIdx.x * 256 + threadIdx.x;
  const float4* s = (const float4*)in;
  float4 a = s[i * 2], b = s[i * 2 + 1];
  us8v o;
  o[0] = f2bf(a.x); o[1] = f2bf(a.y); o[2] = f2bf(a.z); o[3] = f2bf(a.w);
  o[4] = f2bf(b.x); o[5] = f2bf(b.y); o[6] = f2bf(b.z); o[7] = f2bf(b.w);
  *(us8v*)&out[i * 8] = o;
}

// ---------------- transpose+pack weights: dst[c][r] = src[r][c]*scale (bf16) ----
__global__ __launch_bounds__(256) void transpose_pack(
    const float* __restrict__ src, ushort* __restrict__ dst,
    int sC, int dLd, long sBatch, long dBatch, float scale) {
  src += (long)blockIdx.z * sBatch;
  dst += (long)blockIdx.z * dBatch;
  const int r0 = blockIdx.y * 64, c0 = blockIdx.x * 64;
  __shared__ ushort T[64 * 68];
  const int t = threadIdx.x;
#pragma unroll
  for (int i = 0; i < 4; ++i) {
    int ch = t + 256 * i;
    int r = ch >> 4, c4 = ch & 15;
    float4 v = *(const float4*)&src[(long)(r0 + r) * sC + c0 + c4 * 4];
    T[(c4 * 4 + 0) * 68 + r] = f2bf(v.x * scale);
    T[(c4 * 4 + 1) * 68 + r] = f2bf(v.y * scale);
    T[(c4 * 4 + 2) * 68 + r] = f2bf(v.z * scale);
    T[(c4 * 4 + 3) * 68 + r] = f2bf(v.w * scale);
  }
  __syncthreads();
#pragma unroll
  for (int i = 0; i < 4; ++i) {
    int ch = t + 256 * i;
    int c = ch >> 4, r4 = ch & 15;
    ushort4 o;
    o.x = T[c * 68 + r4 * 4 + 0];
    o.y = T[c * 68 + r4 * 4 + 1];
    o.z = T[c * 68 + r4 * 4 + 2];
    o.w = T[c * 68 + r4 * 4 + 3];
    *(ushort4*)&dst[(long)(c0 + c) * dLd + r0 + r4 * 4] = o;
  }
}

// ------ 256x128 bf16 MFMA GEMM, 2-phase counted-vmcnt pipeline (T3/T4 min) ----
// 8 waves (4M x 2N), dbuf LDS 96 KB. Per K-step: stage(next tile, buf^1) async,
// compute(buf) [ds_read swizzled + MFMA], THEN asm vmcnt(0) + raw s_barrier —
// next-tile loads have the whole MFMA phase to land, drain is residual only.
// XOR bank swizzle both sides (pre-swizzled global src col + swizzled ds_read).
// SWZ=0: batch z pinned to XCD. SWZ=1: 4-row band supertile per XCD
// (A-slab 2MB + B col-slice L2-resident).
// EPI 0: scatter Q/K ([B,H,S,64]) + Vt ([B,D,S]); EPI 1: bf16 C; EPI 2: fp32 C
template <int EPI, bool CAUSAL, int SWZ>
__global__ __launch_bounds__(512, 1) void gemm2ph(
    const ushort* __restrict__ A, const ushort* __restrict__ Bt,
    int N, int K, long aB, long bB,
    ushort* __restrict__ O_q, ushort* __restrict__ O_k, ushort* __restrict__ O_v,
    ushort* __restrict__ O_b, long oB,
    float* __restrict__ O_f) {
  __shared__ __align__(16) ushort As[2][256 * 64];  // 2 x 32 KB
  __shared__ __align__(16) ushort Bs[2][128 * 64];  // 2 x 16 KB
  const int tid = threadIdx.x;
  const int lane = tid & 63, w = tid >> 6;
  const int lr = lane & 15, lg = lane >> 4;

  // XCD assignment: hw-linear id %8 = XCD
  const int nx = gridDim.x, ny = gridDim.y;
  long hw = blockIdx.x + (long)nx * (blockIdx.y + (long)ny * blockIdx.z);
  int k8 = (int)(hw & 7);
  long l = hw >> 3;
  int bx, by, z;
  if (SWZ == 1) {              // band supertile: XCD owns ny/8 consecutive rows
    const int BH = ny >> 3;
    by = k8 * BH + (int)(l % BH);
    bx = (int)(l / BH);
    z = 0;
  } else {                     // XCD owns batch z (requires gridDim.z == 8)
    z = k8;
    by = (int)(l % ny);
    bx = (int)(l / ny);
  }

  const int row0 = by * 256, col0 = bx * 128;
  A += (long)z * aB;
  Bt += (long)z * bB;
  const int wr = (w >> 1) * 64, wc = (w & 1) * 64;

  f32x4 acc[4][4] = {};
  const int kmax = CAUSAL ? (K < row0 + 256 ? K : row0 + 256) : K;
  const int nk = kmax >> 6;

  auto stage = [&](int buf, int kt) {
    const int k0 = kt << 6;
#pragma unroll
    for (int j = 0; j < 4; ++j) {    // A: 2048 16B-chunks / 512 thr
      int c = tid + 512 * j;
      int r = c >> 3, c8 = (c & 7) ^ (r & 7);
      gl16(&A[(long)(row0 + r) * K + k0 + c8 * 8], &As[buf][c * 8]);
    }
#pragma unroll
    for (int j = 0; j < 2; ++j) {    // B: 1024 16B-chunks / 512 thr
      int c = tid + 512 * j;
      int r = c >> 3, c8 = (c & 7) ^ (r & 7);
      gl16(&Bt[(long)(col0 + r) * K + k0 + c8 * 8], &Bs[buf][c * 8]);
    }
  };
  auto compute = [&](int buf) {
#pragma unroll
    for (int kk = 0; kk < 2; ++kk) {
      bf16x8 af[4], bfr[4];
#pragma unroll
      for (int m = 0; m < 4; ++m) {
        int row = wr + m * 16 + lr;
        int c8 = (kk * 4 + lg) ^ (row & 7);
        af[m] = ld_bf16x8(&As[buf][row * 64 + c8 * 8]);
      }
#pragma unroll
      for (int n = 0; n < 4; ++n) {
        int row = wc + n * 16 + lr;
        int c8 = (kk * 4 + lg) ^ (row & 7);
        bfr[n] = ld_bf16x8(&Bs[buf][row * 64 + c8 * 8]);
      }
      __builtin_amdgcn_s_setprio(1);
#pragma unroll
      for (int m = 0; m < 4; ++m)
#pragma unroll
        for (int n = 0; n < 4; ++n)
          acc[m][n] = __builtin_amdgcn_mfma_f32_16x16x32_bf16(af[m], bfr[n], acc[m][n], 0, 0, 0);
      __builtin_amdgcn_s_setprio(0);
    }
  };

  stage(0, 0);
  asm volatile("s_waitcnt vmcnt(0)" ::: "memory");
  __builtin_amdgcn_s_barrier();
  __builtin_amdgcn_sched_barrier(0);
  int buf = 0;
  for (int kt = 0; kt < nk - 1; ++kt) {
    stage(buf ^ 1, kt + 1);          // async issue next tile into other buffer
    compute(buf);                    // MFMA on current tile (covers the loads)
    asm volatile("s_waitcnt vmcnt(0)" ::: "memory");
    __builtin_amdgcn_s_barrier();    // one barrier per K-step; drain is residual
    __builtin_amdgcn_sched_barrier(0);
    buf ^= 1;
  }
  compute(buf);

#pragma unroll
  for (int m = 0; m < 4; ++m)
#pragma unroll
    for (int n = 0; n < 4; ++n)
#pragma unroll
      for (int r = 0; r < 4; ++r) {
        int gr = row0 + wr + m * 16 + lg * 4 + r;
        int gc = col0 + wc + n * 16 + lr;
        float v = acc[m][n][r];
        if (EPI == 0) {
          int b = gr >> 10, s = gr & 1023;
          if (gc < 1024) {
            int h = gc >> 6, kq = gc & 63;
            O_q[(((long)(b * 16 + h) << 10) + s) * 64 + kq] = f2bf(v);
          } else if (gc < 2048) {
            int n2 = gc - 1024;
            int h = n2 >> 6, kq = n2 & 63;
            O_k[(((long)(b * 16 + h) << 10) + s) * 64 + kq] = f2bf(v);
          } else {
            int e = gc - 2048;
            O_v[((long)(b << 10) + e) * 1024 + s] = f2bf(v);
          }
        } else if (EPI == 1) {
          (O_b + (long)z * oB)[(long)gr * N + gc] = f2bf(v);
        } else {
          O_f[(long)gr * N + gc] = v;
        }
      }
}

// ---------------- fused masked softmax, head-averaged attention (v6) ----------
// grid (32, 8) = 256 blocks (1/CU, 1 round), 512 threads = 8 waves. Block owns
// the PAIR (qt = x2, qt = 63-x2): uniform work, shared K staging. K staged per
// head into double-buffered LDS halves; stage drains covered by QK phases.
__global__ __launch_bounds__(512, 2) void attn16(
    const ushort* __restrict__ Qb, const ushort* __restrict__ Kb,
    const float* __restrict__ mask, float* __restrict__ attn_out,
    ushort* __restrict__ attnb) {
  __shared__ __align__(16) ushort Ks[2][4 * 128 * 64];  // 2 x 64 KB
  __shared__ float redS[2][8][16];
  const int tid = threadIdx.x;
  const int lane = tid & 63, w = tid >> 6;   // wave owns s-cols w*16+lr per 128-strip
  const int lr = lane & 15, lg = lane >> 4;
  const int hw = blockIdx.x + 32 * blockIdx.y;
  const int b = hw & 7;                      // linear id %8 = XCD: pin batch
  const int x2 = hw >> 3;                    // 0..31
  const int q0a = x2 * 16;                   // light tile (strips 0..3 only)
  const int q0b = (63 - x2) * 16;            // heavy tile (512..1008)
  const int NTb = ((63 - x2) >> 3) + 1;      // heavy strips needed: 5..8
  const int n1 = (NTb - 4) << 10;            // g1 chunk count (1024..4096)
  const int NTWa = (x2 >> 4) * 2 + 2;        // strips AV's 256-row tile reads
  const int NTWb = ((63 - x2) >> 4) * 2 + 2;

  float mqa[4], mqb[4], ms[8];
#pragma unroll
  for (int r = 0; r < 4; ++r) {
    mqa[r] = mask[b * 1024 + q0a + lg * 4 + r];
    mqb[r] = mask[b * 1024 + q0b + lg * 4 + r];
  }
#pragma unroll
  for (int t = 0; t < 8; ++t) ms[t] = mask[b * 1024 + t * 128 + w * 16 + lr];

  auto stageG = [&](int buf, int t0, int nch, int h) {
    const long hb = ((long)(b * 16 + h)) << 10;
#pragma unroll 2
    for (int i = tid; i < nch; i += 512) {
      int j = i >> 10, r = (i >> 3) & 127, c8 = i & 7;
      gl16(&Kb[(hb + (t0 + j) * 128 + r) * 64 + ((c8 ^ (r & 7)) << 3)],
           &Ks[buf][i * 8]);
    }
  };

  const int row = w * 16 + lr;
  const int cs0 = ((0 + lg) ^ (row & 7)) * 8;   // swizzled byte cols kk=0/1
  const int cs1 = ((4 + lg) ^ (row & 7)) * 8;

  stageG(0, 0, 4096, 0);
  __syncthreads();   // prologue drain

  f32x4 acca[4] = {};
  f32x4 accb[8] = {};
#pragma unroll 1
  for (int h = 0; h < 16; ++h) {
    const long hb = ((long)(b * 16 + h)) << 10;
    const bf16x8 qa0 = ld_bf16x8(&Qb[(hb + q0a + lr) * 64 + lg * 8]);
    const bf16x8 qa1 = ld_bf16x8(&Qb[(hb + q0a + lr) * 64 + 32 + lg * 8]);
    const bf16x8 qb0 = ld_bf16x8(&Qb[(hb + q0b + lr) * 64 + lg * 8]);
    const bf16x8 qb1 = ld_bf16x8(&Qb[(hb + q0b + lr) * 64 + 32 + lg * 8]);

    stageG(1, 4, n1, h);   // issue g1 strips; covered by QK(g0) below

    f32x4 sca[4], scb[8];
    float psa[4] = {0.f, 0.f, 0.f, 0.f}, psb[4] = {0.f, 0.f, 0.f, 0.f};
    // ---- QK group 0: strips 0..3 from Ks[0] ----
#pragma unroll
    for (int t = 0; t < 4; ++t) {
      const int sb = t * 128 + w * 16;
      const ushort* kr = &Ks[0][(t * 128 + row) * 64];
      bf16x8 k0 = ld_bf16x8(kr + cs0);
      bf16x8 k1 = ld_bf16x8(kr + cs1);
      {  // heavy tile: sb <= 496 < 512 <= q0b always
        f32x4 d = {};
        d = __builtin_amdgcn_mfma_f32_16x16x32_bf16(qb0, k0, d, 0, 0, 0);
        d = __builtin_amdgcn_mfma_f32_16x16x32_bf16(qb1, k1, d, 0, 0, 0);
#pragma unroll
        for (int r = 0; r < 4; ++r) {
          float e = __expf(d[r]) * (mqb[r] * ms[t]);
          scb[t][r] = e;
          psb[r] += e;
        }
      }
      if (sb <= q0a) {  // light tile
        f32x4 d = {};
        d = __builtin_amdgcn_mfma_f32_16x16x32_bf16(qa0, k0, d, 0, 0, 0);
        d = __builtin_amdgcn_mfma_f32_16x16x32_bf16(qa1, k1, d, 0, 0, 0);
#pragma unroll
        for (int r = 0; r < 4; ++r) {
          float e = __expf(d[r]) * (mqa[r] * ms[t]);
          if (sb == q0a) e = (lr <= lg * 4 + r) ? e : 0.f;
          sca[t][r] = e;
          psa[r] += e;
        }
      }
    }
    __syncthreads();   // drain g1 stage; Ks[0] reads done

    if (h < 15) stageG(0, 0, 4096, h + 1);  // issue next head g0; covered by QK(g1)

    // ---- QK group 1: strips 4..7 from Ks[1] ----
#pragma unroll
    for (int t = 4; t < 8; ++t) {
      const int sb = t * 128 + w * 16;
      if (sb <= q0b) {
        const ushort* kr = &Ks[1][((t - 4) * 128 + row) * 64];
        bf16x8 k0 = ld_bf16x8(kr + cs0);
        bf16x8 k1 = ld_bf16x8(kr + cs1);
        f32x4 d = {};
        d = __builtin_amdgcn_mfma_f32_16x16x32_bf16(qb0, k0, d, 0, 0, 0);
        d = __builtin_amdgcn_mfma_f32_16x16x32_bf16(qb1, k1, d, 0, 0, 0);
#pragma unroll
        for (int r = 0; r < 4; ++r) {
          float e = __expf(d[r]) * (mqb[r] * ms[t]);
          if (sb == q0b) e = (lr <= lg * 4 + r) ? e : 0.f;
          scb[t][r] = e;
          psb[r] += e;
        }
      }
    }
    // row-sums: 16-lane shfl reduce, then cross-wave via LDS
#pragma unroll
    for (int r = 0; r < 4; ++r) {
      psa[r] += __shfl_xor(psa[r], 1);
      psa[r] += __shfl_xor(psa[r], 2);
      psa[r] += __shfl_xor(psa[r], 4);
      psa[r] += __shfl_xor(psa[r], 8);
      psb[r] += __shfl_xor(psb[r], 1);
      psb[r] += __shfl_xor(psb[r], 2);
      psb[r] += __shfl_xor(psb[r], 4);
      psb[r] += __shfl_xor(psb[r], 8);
    }
    if (lr == 0) {
#pragma unroll
      for (int r = 0; r < 4; ++r) {
        redS[0][w][lg * 4 + r] = psa[r];
        redS[1][w][lg * 4 + r] = psb[r];
      }
    }
    __syncthreads();  // drain next-g0 stage; Ks[1] reads done; redS visible

#pragma unroll
    for (int r = 0; r < 4; ++r) {
      float ta = 0.f, tb = 0.f;
#pragma unroll
      for (int ww = 0; ww < 8; ++ww) {
        ta += redS[0][ww][lg * 4 + r];
        tb += redS[1][ww][lg * 4 + r];
      }
      float ra = __builtin_amdgcn_rcpf(ta);
      float rb = __builtin_amdgcn_rcpf(tb);
#pragma unroll
      for (int t = 0; t < 4; ++t) {
        const int sb = t * 128 + w * 16;
        if (sb <= q0a) acca[t][r] += sca[t][r] * ra;
      }
#pragma unroll
      for (int t = 0; t < 8; ++t) {
        const int sb = t * 128 + w * 16;
        if (sb <= q0b) accb[t][r] += scb[t][r] * rb;
      }
    }
  }  // heads

  // write fp32 attn_avg (d_out) + bf16 copy for strips the AV GEMM reads
#pragma unroll
  for (int t = 0; t < 8; ++t) {
    int s = t * 128 + w * 16 + lr;
#pragma unroll
    for (int r = 0; r < 4; ++r) {
      {
        int q = q0a + lg * 4 + r;
        float v = (t < 4 ? acca[t][r] : 0.f) * 0.0625f;
        long o = ((long)(b * 1024 + q) << 10) + s;
        attn_out[o] = v;
        if (t < NTWa) attnb[o] = f2bf(v);
      }
      {
        int q = q0b + lg * 4 + r;
        float v = accb[t][r] * 0.0625f;
        long o = ((long)(b * 1024 + q) << 10) + s;
        attn_out[o] = v;
        if (t < NTWb) attnb[o] = f2bf(v);
      }
    }
  }
}

// ---------------- launch ----------------
extern "C" void kernel_launch(void* const* d_in, const int* in_sizes, int n_in,
                              void* d_out, int out_size, void* d_ws, size_t ws_size,
                              hipStream_t stream) {
  const float* inputs = (const float*)d_in[0];
  const float* mask   = (const float*)d_in[1];
  const float* W_q    = (const float*)d_in[2];
  const float* W_k    = (const float*)d_in[3];
  const float* W_v    = (const float*)d_in[4];
  const float* W_o    = (const float*)d_in[5];
  float* out = (float*)d_out;

  ushort* Xb    = (ushort*)d_ws;            // [8192][1024]
  ushort* WqkvT = Xb + 8192L * 1024;        // [3072][1024]  (B^T layout)
  ushort* WoT   = WqkvT + 3072L * 1024;     // [1024][1024]
  ushort* Qb    = WoT + 1024L * 1024;       // [B,H,S,64]
  ushort* Kb    = Qb + 8L * 16 * 1024 * 64; // [B,H,S,64]
  ushort* Vt    = Kb + 8L * 16 * 1024 * 64; // [B,D,S]
  ushort* attnb = Vt + 8L * 1024 * 1024;    // [B,S,S]
  ushort* Houtb = attnb + 8L * 1024 * 1024; // [B,S,D]

  pack_x<<<4096, 256, 0, stream>>>(inputs, Xb);
  transpose_pack<<<dim3(1, 16, 16), 256, 0, stream>>>(W_q, WqkvT, 64, 1024,
                                                      65536L, 64L * 1024, 0.125f);
  transpose_pack<<<dim3(1, 16, 16), 256, 0, stream>>>(W_k, WqkvT + 1024L * 1024, 64, 1024,
                                                      65536L, 64L * 1024, 1.0f);
  transpose_pack<<<dim3(16, 16, 1), 256, 0, stream>>>(W_v, WqkvT + 2048L * 1024, 1024, 1024,
                                                      0L, 0L, 1.0f);
  transpose_pack<<<dim3(16, 16, 1), 256, 0, stream>>>(W_o, WoT, 1024, 1024,
                                                      0L, 0L, 1.0f);
  // QKV projection: [8192,1024] x [1024,3072], 256x128 tiles, 2-phase pipeline,
  // band-supertile XCD mapping (SWZ=1). 768 blocks.
  gemm2ph<0, false, 1><<<dim3(24, 32, 1), 512, 0, stream>>>(
      Xb, WqkvT, 3072, 1024, 0L, 0L, Qb, Kb, Vt, nullptr, 0L, nullptr);
  // masked softmax, head-avg: 256 blocks, paired q-tiles
  attn16<<<dim3(32, 8), 512, 0, stream>>>(Qb, Kb, mask, out + 8388608L, attnb);
  // Hout = attn_avg @ V (causal K-limit), per batch (SWZ=0: z pinned to XCD)
  gemm2ph<1, true, 0><<<dim3(8, 4, 8), 512, 0, stream>>>(
      attnb, Vt, 1024, 1024, 1048576L, 1048576L,
      nullptr, nullptr, nullptr, Houtb, 1048576L, nullptr);
  // output = Hout @ W_o, band-supertile mapping
  gemm2ph<2, false, 1><<<dim3(8, 32, 1), 512, 0, stream>>>(
      Houtb, WoT, 1024, 1024, 0L, 0L,
      nullptr, nullptr, nullptr, nullptr, 0L, out);
}